// Round 3
// baseline (11504.787 us; speedup 1.0000x reference)
//
#include <hip/hip_runtime.h>

// NODE scan, dual-stream pipelined: 64 groups x 8 blocks; group = 8 batch rows.
// Each block serves member j of TWO groups (S0=g, S1=g+32) and interleaves
// their phases so every flag release has a full compute slot before the
// matching wait (sync latency hidden under the other stream's compute).
// Cross-block traffic via write-through (sc0 sc1) loads/stores, no fences.

#define TT 1000
#define II 16
#define LL 128
#define HH 512
#define OO 64
#define BB 512

typedef _Float16 f16;
typedef _Float16 f16x8 __attribute__((ext_vector_type(8)));
typedef _Float16 f16x4 __attribute__((ext_vector_type(4)));
typedef float    f32x4 __attribute__((ext_vector_type(4)));
typedef unsigned u32x2 __attribute__((ext_vector_type(2)));
typedef unsigned u32x4 __attribute__((ext_vector_type(4)));

#define MFMA16(a, b, c) __builtin_amdgcn_mfma_f32_16x16x32_f16((a), (b), (c), 0, 0, 0)

// LDS K-strides (f16): dword-stride % 32 == 4 or 20 -> frag rows spread banks
#define ZS  520   // act: z (K=160) / a1 (K=512) / a2-chunk (K=64) / vp-lds (64..191)
#define W1S 168   // K=160 (144 + zero pad)
#define W3S 72    // K=64 (row-slice of W3)
#define WRS 136   // K=128

struct Lds {
  f16 w1t[64][W1S];     // W1^T col-slice: [n=64][k=160]
  f16 w2t[64][ZS];      // W2^T col-slice: [n=64][k=512]
  f16 w3t[128][W3S];    // W3^T row-slice: [n=128][k=64 local]
  f16 wrt[16][WRS];     // Wr^T slice (8 real cols + 8 zero)
  f16 act[2][16][ZS];   // per-stream z / a1 / a2-chunk / vp staging
  float h[2][8][LL];    // per-stream fp32 running state (8 rows)
  float b1c[64], b2c[64], b3c[128], brc[16];
};

// ---- write-through (coherent via L2/L3) primitives ----
__device__ __forceinline__ void st_thru_u32(void* p, unsigned v) {
  asm volatile("global_store_dword %0, %1, off sc0 sc1" :: "v"(p), "v"(v) : "memory");
}
__device__ __forceinline__ void st_thru_u2(void* p, u32x2 v) {
  asm volatile("global_store_dwordx2 %0, %1, off sc0 sc1" :: "v"(p), "v"(v) : "memory");
}
__device__ __forceinline__ void st_thru_u4(void* p, u32x4 v) {
  asm volatile("global_store_dwordx4 %0, %1, off sc0 sc1" :: "v"(p), "v"(v) : "memory");
}
__device__ __forceinline__ u32x4 ld_thru_u4(const void* p) {
  u32x4 r;
  asm volatile("global_load_dwordx4 %0, %1, off sc0 sc1" : "=v"(r) : "v"(p) : "memory");
  return r;
}
__device__ __forceinline__ unsigned ld_thru_u32(const void* p) {
  unsigned r;
  asm volatile("global_load_dword %0, %1, off sc0 sc1\n\ts_waitcnt vmcnt(0)"
               : "=v"(r) : "v"(p) : "memory");
  return r;
}
__device__ __forceinline__ void vm_drain() {
  asm volatile("s_waitcnt vmcnt(0)" ::: "memory");
  __builtin_amdgcn_sched_barrier(0);   // rule #18
}

__launch_bounds__(256, 1)
__global__ void node_scan_kernel(
    const float* __restrict__ x,
    const float* __restrict__ W1, const float* __restrict__ b1,
    const float* __restrict__ W2, const float* __restrict__ b2,
    const float* __restrict__ W3, const float* __restrict__ b3,
    const float* __restrict__ Wr, const float* __restrict__ br,
    float* __restrict__ out,
    unsigned* __restrict__ flags,
    f16* __restrict__ a1buf, f16* __restrict__ vpbuf)
{
  __shared__ Lds s;
  const int tid  = threadIdx.x;
  const int bid  = blockIdx.x;
  const int j    = (bid >> 3) & 7;                 // member 0..7
  const int g0   = (bid & 7) + 8 * ((bid >> 6) & 3);   // group 0..31 (same XCD heuristic)
  const int g1   = g0 + 32;                        // second stream's group
  const int lane = tid & 63;
  const int w    = tid >> 6;
  const int lr   = lane & 15;
  const int lk   = lane >> 4;

  float* lat = out + (size_t)BB * TT * OO;

  // ---------------- prologue: weights -> LDS (transposed, f16) ------------
  { int n = tid & 63, ks = tid >> 6;
    for (int k = ks; k < 144; k += 4)       s.w1t[n][k] = (f16)W1[(size_t)k * HH + 64 * j + n];
    for (int k = 144 + ks; k < W1S; k += 4) s.w1t[n][k] = (f16)0.f;
    for (int k = ks; k < HH; k += 4)        s.w2t[n][k] = (f16)W2[(size_t)k * HH + 64 * j + n];
  }
  for (int idx = tid; idx < 128 * 64; idx += 256) {   // W3 rows 64j..64j+63
    int kl = idx >> 7, n = idx & 127;
    s.w3t[n][kl] = (f16)W3[(size_t)(64 * j + kl) * LL + n];
  }
  { int n = tid & 15, ks = tid >> 4;
    for (int k = ks; k < LL; k += 16)
      s.wrt[n][k] = (n < 8) ? (f16)Wr[(size_t)k * OO + 8 * j + n] : (f16)0.f;
  }
  if (tid < 64)       { s.b1c[tid] = b1[64 * j + tid]; s.b2c[tid] = b2[64 * j + tid]; }
  else if (tid < 192) { s.b3c[tid - 64] = b3[tid - 64]; }
  else if (tid < 208) { int n = tid - 192; s.brc[n] = (n < 8) ? br[8 * j + n] : 0.f; }
  for (int i = tid; i < 2 * 8 * LL; i += 256) ((float*)s.h)[i] = 0.f;
  for (int i = tid; i < 2 * 16 * ZS; i += 256) ((f16*)s.act)[i] = (f16)0.f;
  __syncthreads();
  size_t xo0 = 0, xo1 = 0;
  if (tid < 128) {
    const int r = tid >> 4, cc = tid & 15;
    xo0 = (size_t)(g0 * 8 + r) * TT * II + cc;
    xo1 = (size_t)(g1 * 8 + r) * TT * II + cc;
    s.act[0][r][128 + cc] = (f16)x[xo0];   // z_0 = [0 | x_0 | 0]
    s.act[1][r][128 + cc] = (f16)x[xo1];
  }
  __syncthreads();

  unsigned* const flS0 = flags + g0 * 32;   // [0..7]=a1 flags, [8..15]=vp flags
  unsigned* const flS1 = flags + g1 * 32;
  float xr0 = 0.f, xr1 = 0.f;

  // ---------------- phase lambdas ----------------
  auto WAIT = [&](unsigned* f, unsigned tgt) {
    if (tid < 8) {
      const unsigned* fp = f + tid;
      while (ld_thru_u32(fp) < tgt) { }
    }
    __syncthreads();
  };
  auto REL = [&](unsigned* fp, unsigned val) {
    vm_drain();
    __syncthreads();
    if (tid == 0) st_thru_u32(fp, val);
  };

  // A: a1_chunk = relu(z @ W1_slice + b1); swapped operands -> lane holds
  // 4 consecutive n for fixed m -> one 8B thru-store per (lr<8) lane.
  auto phaseA = [&](int si, int t) {
    const int gS = si ? g1 : g0;
    f16* a1b = a1buf + (size_t)(gS * 2 + (t & 1)) * 4096;   // [m=8][n=512]
    f32x4 c = {0.f, 0.f, 0.f, 0.f};
#pragma unroll
    for (int kt = 0; kt < 5; ++kt) {
      f16x8 wf = *(const f16x8*)&s.w1t[w * 16 + lr][kt * 32 + lk * 8];
      f16x8 zf = *(const f16x8*)&s.act[si][lr][kt * 32 + lk * 8];
      c = MFMA16(wf, zf, c);    // D[n_local][m]
    }
    if (lr < 8) {
      f16x4 o;
#pragma unroll
      for (int e = 0; e < 4; ++e) {
        float vv = c[e] + s.b1c[w * 16 + lk * 4 + e];
        vv = vv > 0.f ? vv : 0.f;
        o[e] = (f16)vv;
      }
      st_thru_u2(a1b + (size_t)lr * 512 + 64 * j + w * 16 + lk * 4,
                 __builtin_bit_cast(u32x2, o));
    }
  };

  auto stageA1 = [&](int si, int t) {   // full a1 [8,512] f16 -> act rows 0..7
    const int gS = si ? g1 : g0;
    const f16* a1b = a1buf + (size_t)(gS * 2 + (t & 1)) * 4096;
    u32x4 t0 = ld_thru_u4(a1b + (size_t)tid * 8);
    u32x4 t1 = ld_thru_u4(a1b + (size_t)(tid + 256) * 8);
    vm_drain();
    *(u32x4*)&s.act[si][tid >> 6][(tid & 63) * 8] = t0;
    *(u32x4*)&s.act[si][(tid + 256) >> 6][(tid & 63) * 8] = t1;
    __syncthreads();
  };

  auto phaseB = [&](int si) {   // a2_chunk = relu(a1 @ W2_slice + b2) -> act[:, 0..63]
    const int bn = w * 16 + lr;
    f32x4 c0 = {0.f, 0.f, 0.f, 0.f}, c1 = {0.f, 0.f, 0.f, 0.f};
#pragma unroll
    for (int kt = 0; kt < 16; kt += 2) {
      f16x8 a0 = *(const f16x8*)&s.act[si][lr][kt * 32 + lk * 8];
      f16x8 b0 = *(const f16x8*)&s.w2t[bn][kt * 32 + lk * 8];
      c0 = MFMA16(a0, b0, c0);
      f16x8 a1_ = *(const f16x8*)&s.act[si][lr][(kt + 1) * 32 + lk * 8];
      f16x8 b1_ = *(const f16x8*)&s.w2t[bn][(kt + 1) * 32 + lk * 8];
      c1 = MFMA16(a1_, b1_, c1);
    }
    __syncthreads();             // all waves done reading a1
#pragma unroll
    for (int e = 0; e < 4; ++e) {
      float vv = c0[e] + c1[e] + s.b2c[bn];
      vv = vv > 0.f ? vv : 0.f;
      s.act[si][lk * 4 + e][bn] = (f16)vv;
    }
    __syncthreads();
  };

  // C': vp = a2_chunk @ W3_rows; frags -> LDS cols 64..191, then coalesced
  // 16B thru-stores of the [8][128] tile.
  auto phaseC = [&](int si, int t) {
    const int gS = si ? g1 : g0;
    f16* vpb = vpbuf + (size_t)(gS * 2 + (t & 1)) * 8192;
    const int nt0 = 2 * w, nt1 = 2 * w + 1;
    f32x4 c0 = {0.f, 0.f, 0.f, 0.f}, c1 = {0.f, 0.f, 0.f, 0.f};
#pragma unroll
    for (int kt = 0; kt < 2; ++kt) {
      f16x8 a  = *(const f16x8*)&s.act[si][lr][kt * 32 + lk * 8];
      f16x8 b0 = *(const f16x8*)&s.w3t[nt0 * 16 + lr][kt * 32 + lk * 8];
      c0 = MFMA16(a, b0, c0);
      f16x8 b1_ = *(const f16x8*)&s.w3t[nt1 * 16 + lr][kt * 32 + lk * 8];
      c1 = MFMA16(a, b1_, c1);
    }
#pragma unroll
    for (int e = 0; e < 4; ++e) {   // write cols >=64: no hazard w/ a2 reads
      s.act[si][lk * 4 + e][64 + nt0 * 16 + lr] = (f16)c0[e];
      s.act[si][lk * 4 + e][64 + nt1 * 16 + lr] = (f16)c1[e];
    }
    __syncthreads();
    if (tid < 128) {
      u32x4 v = *(const u32x4*)&s.act[si][tid >> 4][64 + (tid & 15) * 8];
      st_thru_u4(vpb + (size_t)j * 1024 + (size_t)tid * 8, v);
    }
  };

  // D: v = sum_j vp_j + b3; h += 0.1 v; rebuild z; write latents slice.
  auto phaseD = [&](int si, int t, float xr) {
    const int gS = si ? g1 : g0;
    const f16* vpb = vpbuf + (size_t)(gS * 2 + (t & 1)) * 8192;
    if (tid < 128) {
      const int r = tid >> 4, c8 = (tid & 15) * 8;
      const f16* vb = vpb + r * 128 + c8;
      u32x4 p[8];
#pragma unroll
      for (int m = 0; m < 8; ++m) p[m] = ld_thru_u4(vb + (size_t)m * 1024);
      vm_drain();
      float sum[8] = {0.f, 0.f, 0.f, 0.f, 0.f, 0.f, 0.f, 0.f};
#pragma unroll
      for (int m = 0; m < 8; ++m) {
        f16x8 ph = __builtin_bit_cast(f16x8, p[m]);
#pragma unroll
        for (int e = 0; e < 8; ++e) sum[e] += (float)ph[e];
      }
      float hreg[8];
      f16x8 zf;
#pragma unroll
      for (int e = 0; e < 8; ++e) {
        float hv = s.h[si][r][c8 + e] + 0.1f * (sum[e] + s.b3c[c8 + e]);
        s.h[si][r][c8 + e] = hv;
        hreg[e] = hv;
        zf[e] = (f16)hv;
      }
      *(f16x8*)&s.act[si][r][c8] = zf;
      const int cc = tid & 15;
      s.act[si][r][128 + cc] = (t + 1 < TT) ? (f16)xr : (f16)0.f;
      s.act[si][r][144 + cc] = (f16)0.f;   // re-zero K pad
      if (((tid & 15) >> 1) == j) {        // this thread's cols = member's slice
        float* dst = lat + ((size_t)(gS * 8 + r) * TT + t) * LL + c8;
        *(f32x4*)dst = *(f32x4*)&hreg[0];
        *(f32x4*)(dst + 4) = *(f32x4*)&hreg[4];
      }
    }
    __syncthreads();
  };

  auto wrOut = [&](int si, int t) {   // out_t = h_t @ Wr + br (act holds z_{t+1})
    if (w == 0) {
      const int gS = si ? g1 : g0;
      f32x4 c = {0.f, 0.f, 0.f, 0.f};
#pragma unroll
      for (int kt = 0; kt < 4; ++kt) {
        f16x8 a = *(const f16x8*)&s.act[si][lr][kt * 32 + lk * 8];
        f16x8 b = *(const f16x8*)&s.wrt[lr][kt * 32 + lk * 8];
        c = MFMA16(a, b, c);
      }
      if (lr < 8 && lk < 2) {
#pragma unroll
        for (int e = 0; e < 4; ++e)
          out[((size_t)(gS * 8 + lk * 4 + e) * TT + t) * OO + 8 * j + lr] =
              c[e] + s.brc[lr];
      }
    }
  };

  // ---------------- pipeline prime: A(S1,0) ----------------
  phaseA(1, 0);
  REL(flS1 + j, 1u);

  // ---------------- main loop: 4 slots, every wait has 1 slot of gap -------
  for (int t = 0; t < TT; ++t) {
    // P1: finish S0 step t-1, start S0 step t
    if (t > 0) {
      WAIT(flS0 + 8, (unsigned)t);
      phaseD(0, t - 1, xr0);
      phaseA(0, t);
      REL(flS0 + j, (unsigned)(t + 1));
      wrOut(0, t - 1);
    } else {
      phaseA(0, 0);
      REL(flS0 + j, 1u);
    }
    if (tid < 128 && t + 1 < TT) {   // x prefetch in the gap
      xr0 = x[xo0 + (size_t)(t + 1) * II];
      xr1 = x[xo1 + (size_t)(t + 1) * II];
    }
    // P2: middle of S1 step t
    WAIT(flS1, (unsigned)(t + 1));
    stageA1(1, t);
    phaseB(1);
    phaseC(1, t);
    REL(flS1 + 8 + j, (unsigned)(t + 1));
    // P3: middle of S0 step t
    WAIT(flS0, (unsigned)(t + 1));
    stageA1(0, t);
    phaseB(0);
    phaseC(0, t);
    REL(flS0 + 8 + j, (unsigned)(t + 1));
    // P4: finish S1 step t, start S1 step t+1
    WAIT(flS1 + 8, (unsigned)(t + 1));
    phaseD(1, t, xr1);
    if (t + 1 < TT) {
      phaseA(1, t + 1);
      REL(flS1 + j, (unsigned)(t + 2));
      wrOut(1, t);
    } else {
      wrOut(1, t);
    }
  }
  // epilogue: finish S0 step TT-1
  WAIT(flS0 + 8, (unsigned)TT);
  phaseD(0, TT - 1, xr0);
  wrOut(0, TT - 1);
}

extern "C" void kernel_launch(void* const* d_in, const int* in_sizes, int n_in,
                              void* d_out, int out_size, void* d_ws, size_t ws_size,
                              hipStream_t stream) {
  const float* x  = (const float*)d_in[0];
  const float* W1 = (const float*)d_in[1];
  const float* b1 = (const float*)d_in[2];
  const float* W2 = (const float*)d_in[3];
  const float* b2 = (const float*)d_in[4];
  const float* W3 = (const float*)d_in[5];
  const float* b3 = (const float*)d_in[6];
  const float* Wr = (const float*)d_in[7];
  const float* br = (const float*)d_in[8];
  float* out = (float*)d_out;

  // ws: [0,8K) flags (64 groups x 32 u32) | 1MB a1buf f16 (64g x 2par x 8x512)
  //     | 2MB vpbuf f16 (64g x 2par x 8memb x 8x128)
  unsigned* flags = (unsigned*)d_ws;
  f16* a1buf = (f16*)((char*)d_ws + 8192);
  f16* vpbuf = (f16*)((char*)d_ws + 8192 + (1 << 20));

  hipMemsetAsync(d_ws, 0, 8192, stream);   // reset flags every launch/replay
  node_scan_kernel<<<256, 256, 0, stream>>>(x, W1, b1, W2, b2, W3, b3, Wr, br,
                                            out, flags, a1buf, vpbuf);
}

// Round 5
// 6110.159 us; speedup vs baseline: 1.8829x; 1.8829x over previous
//
#include <hip/hip_runtime.h>

// NODE scan: 32 groups x 8 blocks; group = 16 batch rows; block j owns a
// 64-col slice of W1/W2, 64-ROW slice of W3 (partial-v reduce), 8 cols of Wr.
// Control plane (flags/polls): ALWAYS sc0 sc1 (L3-coherent, R2-proven live).
// Data plane (a1/vp payloads): sc0-only (XCD-L2) iff a startup probe PROVES
// sc0 store->drain->load coherence incl. stale-L1 detection; else sc0 sc1.
// No spin loop ever waits on an sc0 value -> no hang path.

#define TT 1000
#define II 16
#define LL 128
#define HH 512
#define OO 64
#define BB 512

typedef _Float16 f16;
typedef _Float16 f16x8 __attribute__((ext_vector_type(8)));
typedef _Float16 f16x4 __attribute__((ext_vector_type(4)));
typedef float    f32x4 __attribute__((ext_vector_type(4)));
typedef unsigned u32x2 __attribute__((ext_vector_type(2)));
typedef unsigned u32x4 __attribute__((ext_vector_type(4)));

#define MFMA16(a, b, c) __builtin_amdgcn_mfma_f32_16x16x32_f16((a), (b), (c), 0, 0, 0)

#define ZS  520   // act K-stride: z(0..159)/a1(0..511)/a2(0..63)/vpT(64..191)
#define W1S 168   // K=160 (144 + zero pad)
#define W3S 72    // K=64 (row-slice of W3)
#define WRS 136   // K=128
#define HPAD 132  // fp32 h stride

struct Lds {
  f16 w1t[64][W1S];
  f16 w2t[64][ZS];
  f16 w3t[128][W3S];
  f16 wrt[16][WRS];
  f16 act[16][ZS];
  float h[16][HPAD];
  float b1c[64], b2c[64], b3c[128], brc[16];
  int xtmp[8];
};

// ---- control-plane primitives: ALWAYS device/system coherent (sc0 sc1) ----
__device__ __forceinline__ void st_sc1_u32(void* p, unsigned v) {
  asm volatile("global_store_dword %0, %1, off sc0 sc1" :: "v"(p), "v"(v) : "memory");
}
__device__ __forceinline__ unsigned ld_sc1_u32(const void* p) {
  unsigned r;
  asm volatile("global_load_dword %0, %1, off sc0 sc1\n\ts_waitcnt vmcnt(0)"
               : "=v"(r) : "v"(p) : "memory");
  return r;
}
// ---- data-plane primitives: FAST = sc0 (XCD L2), SLOW = sc0 sc1 (L3) ----
__device__ __forceinline__ void st_sc0_u32(void* p, unsigned v) {
  asm volatile("global_store_dword %0, %1, off sc0" :: "v"(p), "v"(v) : "memory");
}
__device__ __forceinline__ unsigned ld_sc0_u32(const void* p) {
  unsigned r;
  asm volatile("global_load_dword %0, %1, off sc0\n\ts_waitcnt vmcnt(0)"
               : "=v"(r) : "v"(p) : "memory");
  return r;
}
template <bool FAST> __device__ __forceinline__ void st_c_u2(void* p, u32x2 v) {
  if constexpr (FAST) asm volatile("global_store_dwordx2 %0, %1, off sc0"     :: "v"(p), "v"(v) : "memory");
  else                asm volatile("global_store_dwordx2 %0, %1, off sc0 sc1" :: "v"(p), "v"(v) : "memory");
}
template <bool FAST> __device__ __forceinline__ void st_c_u4(void* p, u32x4 v) {
  if constexpr (FAST) asm volatile("global_store_dwordx4 %0, %1, off sc0"     :: "v"(p), "v"(v) : "memory");
  else                asm volatile("global_store_dwordx4 %0, %1, off sc0 sc1" :: "v"(p), "v"(v) : "memory");
}
template <bool FAST> __device__ __forceinline__ u32x4 ld_c_u4(const void* p) {
  u32x4 r;
  if constexpr (FAST) asm volatile("global_load_dwordx4 %0, %1, off sc0"     : "=v"(r) : "v"(p) : "memory");
  else                asm volatile("global_load_dwordx4 %0, %1, off sc0 sc1" : "=v"(r) : "v"(p) : "memory");
  return r;
}
__device__ __forceinline__ void vm_drain() {
  asm volatile("s_waitcnt vmcnt(0)" ::: "memory");
  __builtin_amdgcn_sched_barrier(0);   // rule #18
}

template <bool FAST>
__device__ void run_loop(Lds& s, const float* __restrict__ x,
                         float* __restrict__ out, float* __restrict__ lat,
                         unsigned* __restrict__ fl,
                         f16* __restrict__ a1buf, f16* __restrict__ vpbuf,
                         int j, int g, int tid, int w, int lr, int lk) {
  const int r  = tid >> 4;
  const int cg = tid & 15;
  const size_t xoff = (size_t)(g * 16 + r) * TT * II + cg;
  float xr = 0.f;
  float hreg[8] = {0.f, 0.f, 0.f, 0.f, 0.f, 0.f, 0.f, 0.f};

  for (int t = 0; t < TT; ++t) {
    const int par = t & 1;
    f16* const a1b = a1buf + (size_t)(g * 2 + par) * (16 * 512);
    f16* const vpb = vpbuf + (size_t)(g * 2 + par) * (8 * 16 * 128);

    // -------- phase A: a1_chunk = relu(z @ W1_slice + b1) ------------------
    // swapped operands: lane holds a1[m=lr][n = w*16+4*lk+e] -> one 8B store.
    {
      f32x4 c = {0.f, 0.f, 0.f, 0.f};
#pragma unroll
      for (int kt = 0; kt < 5; ++kt) {
        f16x8 wf = *(const f16x8*)&s.w1t[w * 16 + lr][kt * 32 + lk * 8];
        f16x8 zf = *(const f16x8*)&s.act[lr][kt * 32 + lk * 8];
        c = MFMA16(wf, zf, c);
      }
      f16x4 o;
#pragma unroll
      for (int e = 0; e < 4; ++e) {
        float vv = c[e] + s.b1c[w * 16 + lk * 4 + e];
        vv = vv > 0.f ? vv : 0.f;
        o[e] = (f16)vv;
      }
      st_c_u2<FAST>(a1b + (size_t)lr * 512 + 64 * j + w * 16 + lk * 4,
                    __builtin_bit_cast(u32x2, o));
    }
    // REL a1 (R2-identical: drain data, barrier, sc1 flag)
    vm_drain();
    __syncthreads();
    if (tid == 0) st_sc1_u32(fl + j, (unsigned)(t + 1));

    // -------- gap: deferred lat/out stores for t-1, x prefetch -------------
    if (t > 0) {
      if ((cg >> 1) == j) {
        float* dst = lat + ((size_t)(g * 16 + r) * TT + (t - 1)) * LL + cg * 8;
        *(f32x4*)dst = *(f32x4*)&hreg[0];
        *(f32x4*)(dst + 4) = *(f32x4*)&hreg[4];
      }
      if (w == 0) {           // out_{t-1} = h_{t-1} @ Wr + br (act = z_t)
        f32x4 c = {0.f, 0.f, 0.f, 0.f};
#pragma unroll
        for (int kt = 0; kt < 4; ++kt) {
          f16x8 a = *(const f16x8*)&s.act[lr][kt * 32 + lk * 8];
          f16x8 b = *(const f16x8*)&s.wrt[lr][kt * 32 + lk * 8];
          c = MFMA16(a, b, c);
        }
        if (lr < 8) {
#pragma unroll
          for (int e = 0; e < 4; ++e)
            out[((size_t)(g * 16 + lk * 4 + e) * TT + (t - 1)) * OO + 8 * j + lr] =
                c[e] + s.brc[lr];
        }
      }
    }
    xr = (t + 1 < TT) ? x[xoff + (size_t)(t + 1) * II] : 0.f;

    // -------- WAIT a1 flags (sc1), stage full a1 [16,512] -> act -----------
    if (tid < 8) {
      const unsigned* fp = fl + tid;
      while (ld_sc1_u32(fp) < (unsigned)(t + 1)) { }
    }
    __syncthreads();
    {
      u32x4 t0 = ld_c_u4<FAST>(a1b + (size_t)(tid +   0) * 8);
      u32x4 t1 = ld_c_u4<FAST>(a1b + (size_t)(tid + 256) * 8);
      u32x4 t2 = ld_c_u4<FAST>(a1b + (size_t)(tid + 512) * 8);
      u32x4 t3 = ld_c_u4<FAST>(a1b + (size_t)(tid + 768) * 8);
      vm_drain();
      *(u32x4*)&s.act[(tid +   0) >> 6][((tid +   0) & 63) * 8] = t0;
      *(u32x4*)&s.act[(tid + 256) >> 6][((tid + 256) & 63) * 8] = t1;
      *(u32x4*)&s.act[(tid + 512) >> 6][((tid + 512) & 63) * 8] = t2;
      *(u32x4*)&s.act[(tid + 768) >> 6][((tid + 768) & 63) * 8] = t3;
    }
    __syncthreads();

    // -------- phase B: a2_chunk = relu(a1 @ W2_slice + b2) -> act[:,0..63] --
    {
      const int bn = w * 16 + lr;
      f32x4 c0 = {0.f, 0.f, 0.f, 0.f}, c1 = {0.f, 0.f, 0.f, 0.f};
#pragma unroll
      for (int kt = 0; kt < 16; kt += 2) {
        f16x8 a0 = *(const f16x8*)&s.act[lr][kt * 32 + lk * 8];
        f16x8 b0 = *(const f16x8*)&s.w2t[bn][kt * 32 + lk * 8];
        c0 = MFMA16(a0, b0, c0);
        f16x8 a1_ = *(const f16x8*)&s.act[lr][(kt + 1) * 32 + lk * 8];
        f16x8 b1_ = *(const f16x8*)&s.w2t[bn][(kt + 1) * 32 + lk * 8];
        c1 = MFMA16(a1_, b1_, c1);
      }
      __syncthreads();          // all waves done reading a1
#pragma unroll
      for (int e = 0; e < 4; ++e) {
        float vv = c0[e] + c1[e] + s.b2c[bn];
        vv = vv > 0.f ? vv : 0.f;
        s.act[lk * 4 + e][bn] = (f16)vv;
      }
      __syncthreads();
    }

    // -------- phase C: vp = a2_chunk @ W3_rows; LDS-T; coalesced store -----
    {
      const int nt0 = 2 * w, nt1 = 2 * w + 1;
      f32x4 c0 = {0.f, 0.f, 0.f, 0.f}, c1 = {0.f, 0.f, 0.f, 0.f};
#pragma unroll
      for (int kt = 0; kt < 2; ++kt) {
        f16x8 a  = *(const f16x8*)&s.act[lr][kt * 32 + lk * 8];
        f16x8 b0 = *(const f16x8*)&s.w3t[nt0 * 16 + lr][kt * 32 + lk * 8];
        c0 = MFMA16(a, b0, c0);
        f16x8 b1_ = *(const f16x8*)&s.w3t[nt1 * 16 + lr][kt * 32 + lk * 8];
        c1 = MFMA16(a, b1_, c1);
      }
#pragma unroll
      for (int e = 0; e < 4; ++e) {
        s.act[lk * 4 + e][64 + nt0 * 16 + lr] = (f16)c0[e];
        s.act[lk * 4 + e][64 + nt1 * 16 + lr] = (f16)c1[e];
      }
      __syncthreads();
      u32x4 v = *(const u32x4*)&s.act[tid >> 4][64 + (tid & 15) * 8];
      st_c_u4<FAST>(vpb + (size_t)j * 2048 + (size_t)tid * 8, v);
    }
    // REL vp
    vm_drain();
    __syncthreads();
    if (tid == 0) st_sc1_u32(fl + 8 + j, (unsigned)(t + 1));
    // WAIT vp flags (sc1)
    if (tid < 8) {
      const unsigned* fp = fl + 8 + tid;
      while (ld_sc1_u32(fp) < (unsigned)(t + 1)) { }
    }
    __syncthreads();

    // -------- phase D: v = sum_j vp_j + b3; h += 0.1 v; rebuild z ----------
    {
      const f16* vb = vpb + (size_t)r * 128 + cg * 8;
      u32x4 p[8];
#pragma unroll
      for (int m = 0; m < 8; ++m) p[m] = ld_c_u4<FAST>(vb + (size_t)m * 2048);
      vm_drain();
      float sum[8] = {0.f, 0.f, 0.f, 0.f, 0.f, 0.f, 0.f, 0.f};
#pragma unroll
      for (int m = 0; m < 8; ++m) {
        f16x8 ph = __builtin_bit_cast(f16x8, p[m]);
#pragma unroll
        for (int e = 0; e < 8; ++e) sum[e] += (float)ph[e];
      }
      f16x8 zf;
#pragma unroll
      for (int e = 0; e < 8; ++e) {
        float hv = s.h[r][cg * 8 + e] + 0.1f * (sum[e] + s.b3c[cg * 8 + e]);
        s.h[r][cg * 8 + e] = hv;
        hreg[e] = hv;
        zf[e] = (f16)hv;
      }
      *(f16x8*)&s.act[r][cg * 8] = zf;
      s.act[r][128 + cg] = (f16)xr;
      s.act[r][144 + cg] = (f16)0.f;
    }
    __syncthreads();
  }

  // -------- epilogue: lat + out for t = TT-1 --------------------------------
  if ((cg >> 1) == j) {
    float* dst = lat + ((size_t)(g * 16 + r) * TT + (TT - 1)) * LL + cg * 8;
    *(f32x4*)dst = *(f32x4*)&hreg[0];
    *(f32x4*)(dst + 4) = *(f32x4*)&hreg[4];
  }
  if (w == 0) {
    f32x4 c = {0.f, 0.f, 0.f, 0.f};
#pragma unroll
    for (int kt = 0; kt < 4; ++kt) {
      f16x8 a = *(const f16x8*)&s.act[lr][kt * 32 + lk * 8];
      f16x8 b = *(const f16x8*)&s.wrt[lr][kt * 32 + lk * 8];
      c = MFMA16(a, b, c);
    }
    if (lr < 8) {
#pragma unroll
      for (int e = 0; e < 4; ++e)
        out[((size_t)(g * 16 + lk * 4 + e) * TT + (TT - 1)) * OO + 8 * j + lr] =
            c[e] + s.brc[lr];
    }
  }
}

__launch_bounds__(256, 1)
__global__ void node_scan_kernel(
    const float* __restrict__ x,
    const float* __restrict__ W1, const float* __restrict__ b1,
    const float* __restrict__ W2, const float* __restrict__ b2,
    const float* __restrict__ W3, const float* __restrict__ b3,
    const float* __restrict__ Wr, const float* __restrict__ br,
    float* __restrict__ out,
    unsigned* __restrict__ flags, unsigned* __restrict__ xccbuf,
    unsigned* __restrict__ pflag, unsigned* __restrict__ pack,
    unsigned* __restrict__ verd,  unsigned* __restrict__ pdata,
    f16* __restrict__ a1buf, f16* __restrict__ vpbuf)
{
  __shared__ Lds s;
  const int tid  = threadIdx.x;
  const int bid  = blockIdx.x;
  const int q    = bid >> 3;
  const int j    = q & 7;                       // member 0..7
  const int g    = (bid & 7) + 8 * (q >> 3);    // group 0..31 (co-XCD heuristic)
  const int lane = tid & 63;
  const int w    = tid >> 6;
  const int lr   = lane & 15;
  const int lk   = lane >> 4;

  float* lat = out + (size_t)BB * TT * OO;

  // ---------------- prologue: weights -> LDS (transposed, f16) ------------
  { int n = tid & 63, ks = tid >> 6;
    for (int k = ks; k < 144; k += 4)       s.w1t[n][k] = (f16)W1[(size_t)k * HH + 64 * j + n];
    for (int k = 144 + ks; k < W1S; k += 4) s.w1t[n][k] = (f16)0.f;
    for (int k = ks; k < HH; k += 4)        s.w2t[n][k] = (f16)W2[(size_t)k * HH + 64 * j + n];
  }
  for (int idx = tid; idx < 128 * 64; idx += 256) {
    int kl = idx >> 7, n = idx & 127;
    s.w3t[n][kl] = (f16)W3[(size_t)(64 * j + kl) * LL + n];
  }
  { int n = tid & 15, ks = tid >> 4;
    for (int k = ks; k < LL; k += 16)
      s.wrt[n][k] = (n < 8) ? (f16)Wr[(size_t)k * OO + 8 * j + n] : (f16)0.f;
  }
  if (tid < 64)       { s.b1c[tid] = b1[64 * j + tid]; s.b2c[tid] = b2[64 * j + tid]; }
  else if (tid < 192) { s.b3c[tid - 64] = b3[tid - 64]; }
  else if (tid < 208) { int n = tid - 192; s.brc[n] = (n < 8) ? br[8 * j + n] : 0.f; }
  for (int i = tid; i < 16 * HPAD; i += 256) ((float*)s.h)[i] = 0.f;
  for (int i = tid; i < 16 * ZS; i += 256) ((f16*)s.act)[i] = (f16)0.f;

  // ---------------- XCD-placement exchange (sc1, proven live) --------------
  int xcc;
  asm volatile("s_getreg_b32 %0, hwreg(HW_REG_XCC_ID)" : "=s"(xcc));
  xcc &= 15;
  if (tid == 0) { st_sc1_u32(xccbuf + g * 8 + j, 0x100u | (unsigned)xcc); vm_drain(); }
  if (tid < 8) {
    unsigned v;
    const unsigned* p = xccbuf + g * 8 + tid;
    do { v = ld_sc1_u32(p); } while (!(v & 0x100u));
    s.xtmp[tid] = (int)(v & 0xffu);
  }
  __syncthreads();
  bool fast = true;
  for (int k2 = 1; k2 < 8; ++k2) fast = fast && (s.xtmp[k2] == s.xtmp[0]);

  // ---------------- sc0 coherence probe (3 rounds, no sc0 spin) ------------
  unsigned okbit = 1u;
  if (fast) {
    unsigned* pd = pdata + g * 8;
    unsigned* pf = pflag + g * 8;
    unsigned* pa = pack  + g * 8;
    const unsigned X = 0x51A00000u | ((unsigned)j << 4);
#pragma unroll 1
    for (int rnd = 0; rnd < 3; ++rnd) {
      unsigned val = (rnd == 1) ? (X | 1u) : X;   // rnd2 restores X (launch-invariant)
      if (tid == 0) {
        st_sc0_u32(pd + j, val);
        vm_drain();
        st_sc1_u32(pf + j, (unsigned)(rnd + 1));
        vm_drain();
      }
      if (tid < 8) {
        while (ld_sc1_u32(pf + tid) < (unsigned)(rnd + 1)) { }
        if (rnd < 2) {   // rnd0 warms L1 (if bypass broken); rnd1 detects stale
          unsigned exp = 0x51A00000u | ((unsigned)tid << 4) | (rnd == 1 ? 1u : 0u);
          if (ld_sc0_u32(pd + tid) != exp) okbit = 0u;
        }
      }
      __syncthreads();
      if (tid == 0) { st_sc1_u32(pa + j, (unsigned)(rnd + 1)); vm_drain(); }
      if (tid < 8) { while (ld_sc1_u32(pa + tid) < (unsigned)(rnd + 1)) { } }
      __syncthreads();
    }
    if (tid < 8) s.xtmp[tid] = (int)okbit;
    __syncthreads();
    for (int k2 = 0; k2 < 8; ++k2) fast = fast && (s.xtmp[k2] != 0);
  }
  // ---------------- verdict exchange: group-uniform FAST/SLOW --------------
  if (tid == 0) { st_sc1_u32(verd + g * 8 + j, 0x100u | (fast ? 1u : 0u)); vm_drain(); }
  if (tid < 8) {
    unsigned v;
    const unsigned* p = verd + g * 8 + tid;
    do { v = ld_sc1_u32(p); } while (!(v & 0x100u));
    s.xtmp[tid] = (int)(v & 1u);
  }
  __syncthreads();
  bool FASTRUN = true;
  for (int k2 = 0; k2 < 8; ++k2) FASTRUN = FASTRUN && (s.xtmp[k2] != 0);

  // z_0 = [0 | x_0 | 0]
  { const int r = tid >> 4, cc = tid & 15;
    s.act[r][128 + cc] = (f16)x[(size_t)(g * 16 + r) * TT * II + cc]; }
  __syncthreads();

  unsigned* const fl = flags + g * 64;
  if (FASTRUN) run_loop<true >(s, x, out, lat, fl, a1buf, vpbuf, j, g, tid, w, lr, lk);
  else         run_loop<false>(s, x, out, lat, fl, a1buf, vpbuf, j, g, tid, w, lr, lk);
}

extern "C" void kernel_launch(void* const* d_in, const int* in_sizes, int n_in,
                              void* d_out, int out_size, void* d_ws, size_t ws_size,
                              hipStream_t stream) {
  const float* x  = (const float*)d_in[0];
  const float* W1 = (const float*)d_in[1];
  const float* b1 = (const float*)d_in[2];
  const float* W2 = (const float*)d_in[3];
  const float* b2 = (const float*)d_in[4];
  const float* W3 = (const float*)d_in[5];
  const float* b3 = (const float*)d_in[6];
  const float* Wr = (const float*)d_in[7];
  const float* br = (const float*)d_in[8];
  float* out = (float*)d_out;

  // ws: [0,8K) flags | [8K) xcc | [9K) pflag | [10K) pack | [11K) verd   (all
  // sc1-written, memset 0 each launch) | [12K,13K) pdata (sc0, NOT memset —
  // probe round 3 restores it) | [16K) 1MB a1buf | 2MB vpbuf
  unsigned* flags  = (unsigned*)d_ws;
  unsigned* xccbuf = (unsigned*)((char*)d_ws + 8192);
  unsigned* pflag  = (unsigned*)((char*)d_ws + 9216);
  unsigned* pack   = (unsigned*)((char*)d_ws + 10240);
  unsigned* verd   = (unsigned*)((char*)d_ws + 11264);
  unsigned* pdata  = (unsigned*)((char*)d_ws + 12288);
  f16* a1buf = (f16*)((char*)d_ws + 16384);
  f16* vpbuf = (f16*)((char*)d_ws + 16384 + (1 << 20));

  hipMemsetAsync(d_ws, 0, 12288, stream);  // flags/xcc/pflag/pack/verd only
  node_scan_kernel<<<256, 256, 0, stream>>>(x, W1, b1, W2, b2, W3, b3, Wr, br,
                                            out, flags, xccbuf, pflag, pack,
                                            verd, pdata, a1buf, vpbuf);
}